// Round 2
// baseline (368.693 us; speedup 1.0000x reference)
//
#include <hip/hip_runtime.h>
#include <hip/hip_bf16.h>

// Problem constants (from reference):
#define BSZ    64
#define DLEN   65536
#define NNODES 1024
#define NFEATS 256
#define EDIM   256
#define NROWS  (BSZ * NNODES)   // 65536 (b,node) rows

// ---- bf16 helpers (RNE pack, bits unpack) ----
__device__ __forceinline__ unsigned short f2bf(float x) {
  union { float f; unsigned u; } c; c.f = x;
  unsigned r = c.u + 0x7FFFu + ((c.u >> 16) & 1u);
  return (unsigned short)(r >> 16);
}
__device__ __forceinline__ float bf2f(unsigned short b) {
  union { float f; unsigned u; } c; c.u = ((unsigned)b) << 16;
  return c.f;
}

// ---- Pass 1: dedup + last-write-wins scatter into dense slot buffer ----
// pack = ((d+1) << 15) | (bf16(val) >> 1).  Unsigned max over same slot is
// decided by d (distinct per slot within a batch) -> np last-write-wins.
// Empty slot stays 0 (min real pack = 1<<15).
__global__ __launch_bounds__(256) void scatter_kernel(
    const float* __restrict__ x, const int* __restrict__ nid,
    const int* __restrict__ fid, unsigned* __restrict__ pk) {
  int i = blockIdx.x * 256 + threadIdx.x;   // 4,194,304 total, exact multiple
  int b = i >> 16;
  int d = i & 0xFFFF;
  int node = nid[i];
  int feat = fid[i];
  unsigned vb = f2bf(x[i]);
  unsigned pack = (((unsigned)(d + 1)) << 15) | (vb >> 1);
  unsigned slot = ((unsigned)b << 18) | ((unsigned)node << 8) | (unsigned)feat;
  atomicMax(pk + slot, pack);
}

// ---- Pass 2: per-row count + GEMM (vals @ W^T) + epilogue (f32 out) ----
// Block: 256 threads, 64 rows x 256 embeds output tile.
// Thread (te = t&31, tr = t>>5) owns rows tr*8..+8, embeds te*8..+8 (8x8 acc).
// K staged in chunks of 32: W chunk (32x256 f32 = 32KB) + vals (64x33 f32).
__global__ __launch_bounds__(256) void embed_kernel(
    const unsigned* __restrict__ pk, const float* __restrict__ W,
    const float* __restrict__ bias, const float* __restrict__ gemb,
    float* __restrict__ out_emb, float* __restrict__ out_mask) {
  __shared__ float Wc[32][256];     // Wc[f][e], 32 KB
  __shared__ float vals[64][33];    // +1 pad
  __shared__ int counts[64];

  const int t  = threadIdx.x;
  const int te = t & 31;
  const int tr = t >> 5;
  const int row0 = blockIdx.x * 64;

  if (t < 64) counts[t] = 0;

  float acc[8][8];
#pragma unroll
  for (int i = 0; i < 8; ++i)
#pragma unroll
    for (int j = 0; j < 8; ++j) acc[i][j] = 0.f;

  // staging mapping: thread covers row rs = t>>2, feats fb..fb+8 of the chunk
  const int rs = t >> 2;
  const int fb = (t & 3) << 3;
  const unsigned* pkrow = pk + (size_t)(row0 + rs) * NFEATS + fb;

  for (int kc = 0; kc < NFEATS; kc += 32) {
    __syncthreads();  // protect LDS from previous iteration's compute (and counts init)

    // stage packed slot values -> vals[][] + accumulate per-row counts
    uint4 p0 = *(const uint4*)(pkrow + kc);
    uint4 p1 = *(const uint4*)(pkrow + kc + 4);
    unsigned pv[8] = {p0.x, p0.y, p0.z, p0.w, p1.x, p1.y, p1.z, p1.w};
    int c = 0;
#pragma unroll
    for (int jj = 0; jj < 8; ++jj) {
      unsigned p = pv[jj];
      float v = 0.f;
      if (p) { ++c; v = bf2f((unsigned short)((p & 0x7FFFu) << 1)); }
      vals[rs][fb + jj] = v;
    }
    if (c) atomicAdd(&counts[rs], c);

    // stage W chunk transposed: thread t = embed row e, reads 32 contiguous k's
    const float* wrow = W + (size_t)t * NFEATS + kc;
#pragma unroll
    for (int q = 0; q < 32; q += 4) {
      float4 w = *(const float4*)(wrow + q);
      Wc[q + 0][t] = w.x; Wc[q + 1][t] = w.y;
      Wc[q + 2][t] = w.z; Wc[q + 3][t] = w.w;
    }
    __syncthreads();

    // compute: acc[i][j] += vals[row][f] * Wc[f][e]
#pragma unroll 4
    for (int f = 0; f < 32; ++f) {
      float4 w0 = *(const float4*)(&Wc[f][te * 8]);
      float4 w1 = *(const float4*)(&Wc[f][te * 8 + 4]);
      float wv[8] = {w0.x, w0.y, w0.z, w0.w, w1.x, w1.y, w1.z, w1.w};
#pragma unroll
      for (int i = 0; i < 8; ++i) {
        float v = vals[tr * 8 + i][f];
#pragma unroll
        for (int j = 0; j < 8; ++j) acc[i][j] += v * wv[j];
      }
    }
  }
  // counts fully accumulated (last atomicAdds were before the last barrier)

  float bj[8];
#pragma unroll
  for (int j = 0; j < 8; ++j) bj[j] = bias[te * 8 + j];

#pragma unroll
  for (int i = 0; i < 8; ++i) {
    int rg = row0 + tr * 8 + i;
    int n  = rg & (NNODES - 1);
    int cnt = counts[tr * 8 + i];
    float s = cnt ? 1.0f / (float)cnt : 0.0f;   // cnt==0 -> nan_to_num => 0
    const float* g = gemb + (size_t)n * EDIM + te * 8;
    float4 g0 = *(const float4*)(g);
    float4 g1 = *(const float4*)(g + 4);
    float gv[8] = {g0.x, g0.y, g0.z, g0.w, g1.x, g1.y, g1.z, g1.w};
    float4 o0, o1;
    o0.x = acc[i][0] * s + bj[0] + gv[0];
    o0.y = acc[i][1] * s + bj[1] + gv[1];
    o0.z = acc[i][2] * s + bj[2] + gv[2];
    o0.w = acc[i][3] * s + bj[3] + gv[3];
    o1.x = acc[i][4] * s + bj[4] + gv[4];
    o1.y = acc[i][5] * s + bj[5] + gv[5];
    o1.z = acc[i][6] * s + bj[6] + gv[6];
    o1.w = acc[i][7] * s + bj[7] + gv[7];
    float* op = out_emb + (size_t)rg * EDIM + te * 8;
    *(float4*)(op)     = o0;
    *(float4*)(op + 4) = o1;
  }

  if (t < 64) {
    int rg = row0 + t;
    out_mask[rg] = (counts[t] == 0) ? 1.0f : 0.0f;
  }
}

extern "C" void kernel_launch(void* const* d_in, const int* in_sizes, int n_in,
                              void* d_out, int out_size, void* d_ws, size_t ws_size,
                              hipStream_t stream) {
  const float* x    = (const float*)d_in[0];   // flat_inputs (64,65536) f32
  const int*   nid  = (const int*)d_in[1];     // node_ids    (64,65536) i32
  const int*   fid  = (const int*)d_in[2];     // feat_ids    (64,65536) i32
  const float* W    = (const float*)d_in[3];   // (256,256) f32, row-major (embed, feat)
  const float* bias = (const float*)d_in[4];   // (256,)
  const float* gemb = (const float*)d_in[5];   // (1024,256) f32

  float* out_emb  = (float*)d_out;                        // f32 (64,1024,256)
  float* out_mask = out_emb + (size_t)NROWS * EDIM;       // f32 (64,1024,1)

  unsigned* pk = (unsigned*)d_ws;
  const size_t pk_bytes = (size_t)NROWS * NFEATS * sizeof(unsigned); // 64 MiB

  hipMemsetAsync(d_ws, 0, pk_bytes, stream);
  scatter_kernel<<<(BSZ * DLEN) / 256, 256, 0, stream>>>(x, nid, fid, pk);
  embed_kernel<<<NROWS / 64, 256, 0, stream>>>(pk, W, bias, gemb, out_emb, out_mask);
}